// Round 7
// baseline (709.760 us; speedup 1.0000x reference)
//
#include <hip/hip_runtime.h>
#include <cstdint>

#define VOCAB_N 50000
#define EMB_N   16
#define HID_N   32
#define B_N     4096
#define T_N     500
#define LOG2E     1.4426950408889634f
#define TWOLOG2E  2.8853900817779268f

typedef __attribute__((ext_vector_type(8))) short bf16x8;
typedef __attribute__((ext_vector_type(4))) float f32x4;
typedef __attribute__((ext_vector_type(4))) unsigned int u32x4;

__device__ __forceinline__ float frcp(float x) { return __builtin_amdgcn_rcpf(x); }

// split: x = hi(bf16) + lo(bf16); packed u32: [15:0]=hi, [31:16]=lo
__device__ __forceinline__ unsigned bf16_split_pack(float x) {
  unsigned u  = __builtin_bit_cast(unsigned, x);
  float hif = __builtin_bit_cast(float, u & 0xFFFF0000u);
  float r   = x - hif;                       // exact
  unsigned lo = __builtin_bit_cast(unsigned, r) >> 16;
  return (u >> 16) | (lo << 16);
}
__device__ __forceinline__ float unpack_h(unsigned p) {
  float hi = __builtin_bit_cast(float, p << 16);
  float lo = __builtin_bit_cast(float, p & 0xFFFF0000u);
  return hi + lo;
}

// physical z-position p (0..127) -> standard gate column (0..127)
// p = 16n + s, s = 4g + r:  col = 32*(n>>1) + 8g + 2r + (n&1)
__device__ __forceinline__ int map_col(int p) {
  int n = p >> 4, s = p & 15;
  int g = s >> 2, r = s & 3;
  return 32 * (n >> 1) + 8 * g + 2 * r + (n & 1);
}
__device__ __forceinline__ float col_scale(int n) {
  return (n == 4 || n == 5) ? TWOLOG2E : LOG2E;   // gamma==2 (g-gate) pre-doubled
}

// ---------------------------------------------------------------------------
// proj[v*128 + p] = scale(p>>4) * (bias[C(p)] + emb[v]·W[:,C(p)])
// ---------------------------------------------------------------------------
__global__ void build_proj_t(const float* __restrict__ emb,
                             const float* __restrict__ W,
                             const float* __restrict__ bias,
                             float* __restrict__ proj) {
  __shared__ float Wl[EMB_N * 128];
  __shared__ float bl[128];
  const int tid = threadIdx.x;
  for (int i = tid; i < EMB_N * 128 / 4; i += 256)
    reinterpret_cast<float4*>(Wl)[i] = reinterpret_cast<const float4*>(W)[i];
  if (tid < 32)
    reinterpret_cast<float4*>(bl)[tid] = reinterpret_cast<const float4*>(bias)[tid];
  __syncthreads();

  const long long gid = (long long)blockIdx.x * 256 + tid;
  if (gid >= (long long)VOCAB_N * 128) return;
  const int v = (int)(gid >> 7);
  const int p = (int)(gid & 127);
  const int col = map_col(p);
  const float sc = col_scale(p >> 4);

  const float4* ev = reinterpret_cast<const float4*>(emb + (size_t)v * EMB_N);
  float4 e0 = ev[0], e1 = ev[1], e2 = ev[2], e3 = ev[3];
  const float em[16] = {e0.x,e0.y,e0.z,e0.w, e1.x,e1.y,e1.z,e1.w,
                        e2.x,e2.y,e2.z,e2.w, e3.x,e3.y,e3.z,e3.w};
  float a = bl[col];
#pragma unroll
  for (int e = 0; e < EMB_N; ++e) a = fmaf(em[e], Wl[e * 128 + col], a);
  proj[gid] = a * sc;
}

// ---------------------------------------------------------------------------
// Lane-closed MFMA scan. 1 wave = 16 batch rows. Lane l = (g = l>>4, c16 = l&15):
//   owns batch row c16, units g8..g8+7 (h, c, all 4 gates) -- fully in-register.
// Per step: 24x mfma_f32_16x16x32_bf16 (A = R^T hi/lo static; B = h hi/lo).
// ---------------------------------------------------------------------------
#define MF(A_, B_, C_) __builtin_amdgcn_mfma_f32_16x16x32_bf16((A_), (B_), (C_), 0, 0, 0)

#define GATE(HP, CC, ZI, ZF, ZG, ZO, R)                                       \
  {                                                                           \
    float zi = (ZI)[R], zf = (ZF)[R], zg = (ZG)[R], zo = (ZO)[R];             \
    float gi = frcp(1.0f + exp2f(-zi));                                       \
    float gf = frcp(1.0f + exp2f(-zf));                                       \
    float gg = fmaf(-2.0f, frcp(1.0f + exp2f(zg)), 1.0f);                     \
    float go = frcp(1.0f + exp2f(-zo));                                       \
    float cn = fmaf(gf, (CC), gi * gg);                                       \
    float tc = fmaf(-2.0f, frcp(1.0f + exp2f(cn * TWOLOG2E)), 1.0f);          \
    float hn = go * tc;                                                       \
    (CC) = mk ? cn : (CC);                                                    \
    unsigned hp_ = bf16_split_pack(hn);                                       \
    (HP) = mk ? hp_ : (HP);                                                   \
  }

#define MBODY(TKC, TKP, XX0, XX1, XX2, XX3, XX4, XX5, XX6, XX7)               \
  {                                                                           \
    /* B-frags from packed h (Bh[j]=hi(h[j]), Bl[j]=lo(h[j])) */              \
    u32x4 bhv, blv;                                                           \
    bhv[0] = __builtin_amdgcn_perm(hp1, hp0, 0x05040100u);                    \
    blv[0] = __builtin_amdgcn_perm(hp1, hp0, 0x07060302u);                    \
    bhv[1] = __builtin_amdgcn_perm(hp3, hp2, 0x05040100u);                    \
    blv[1] = __builtin_amdgcn_perm(hp3, hp2, 0x07060302u);                    \
    bhv[2] = __builtin_amdgcn_perm(hp5, hp4, 0x05040100u);                    \
    blv[2] = __builtin_amdgcn_perm(hp5, hp4, 0x07060302u);                    \
    bhv[3] = __builtin_amdgcn_perm(hp7, hp6, 0x05040100u);                    \
    blv[3] = __builtin_amdgcn_perm(hp7, hp6, 0x07060302u);                    \
    bf16x8 Bh = __builtin_bit_cast(bf16x8, bhv);                              \
    bf16x8 Bl = __builtin_bit_cast(bf16x8, blv);                              \
    f32x4 za0 = __builtin_bit_cast(f32x4, XX0);                               \
    f32x4 za1 = __builtin_bit_cast(f32x4, XX1);                               \
    f32x4 za2 = __builtin_bit_cast(f32x4, XX2);                               \
    f32x4 za3 = __builtin_bit_cast(f32x4, XX3);                               \
    f32x4 za4 = __builtin_bit_cast(f32x4, XX4);                               \
    f32x4 za5 = __builtin_bit_cast(f32x4, XX5);                               \
    f32x4 za6 = __builtin_bit_cast(f32x4, XX6);                               \
    f32x4 za7 = __builtin_bit_cast(f32x4, XX7);                               \
    /* even accs first (feed even-m gates) */                                 \
    za0 = MF(Ah0, Bh, za0); za0 = MF(Ah0, Bl, za0); za0 = MF(Al0, Bh, za0);   \
    za2 = MF(Ah2, Bh, za2); za2 = MF(Ah2, Bl, za2); za2 = MF(Al2, Bh, za2);   \
    za4 = MF(Ah4, Bh, za4); za4 = MF(Ah4, Bl, za4); za4 = MF(Al4, Bh, za4);   \
    za6 = MF(Ah6, Bh, za6); za6 = MF(Ah6, Bl, za6); za6 = MF(Al6, Bh, za6);   \
    /* prefetch xp for t+2 (X regs just consumed) */                          \
    {                                                                         \
      const float* pv = proj + ((size_t)(unsigned)(TKP) << 7) + g4;           \
      XX0 = *reinterpret_cast<const float4*>(pv);                             \
      XX1 = *reinterpret_cast<const float4*>(pv + 16);                        \
      XX2 = *reinterpret_cast<const float4*>(pv + 32);                        \
      XX3 = *reinterpret_cast<const float4*>(pv + 48);                        \
      XX4 = *reinterpret_cast<const float4*>(pv + 64);                        \
      XX5 = *reinterpret_cast<const float4*>(pv + 80);                        \
      XX6 = *reinterpret_cast<const float4*>(pv + 96);                        \
      XX7 = *reinterpret_cast<const float4*>(pv + 112);                       \
    }                                                                         \
    const bool mk = (TKC) != 0;                                               \
    GATE(hp0, cc0, za0, za2, za4, za6, 0)                                     \
    GATE(hp2, cc2, za0, za2, za4, za6, 1)                                     \
    GATE(hp4, cc4, za0, za2, za4, za6, 2)                                     \
    GATE(hp6, cc6, za0, za2, za4, za6, 3)                                     \
    za1 = MF(Ah1, Bh, za1); za1 = MF(Ah1, Bl, za1); za1 = MF(Al1, Bh, za1);   \
    za3 = MF(Ah3, Bh, za3); za3 = MF(Ah3, Bl, za3); za3 = MF(Al3, Bh, za3);   \
    za5 = MF(Ah5, Bh, za5); za5 = MF(Ah5, Bl, za5); za5 = MF(Al5, Bh, za5);   \
    za7 = MF(Ah7, Bh, za7); za7 = MF(Ah7, Bl, za7); za7 = MF(Al7, Bh, za7);   \
    GATE(hp1, cc1, za1, za3, za5, za7, 0)                                     \
    GATE(hp3, cc3, za1, za3, za5, za7, 1)                                     \
    GATE(hp5, cc5, za1, za3, za5, za7, 2)                                     \
    GATE(hp7, cc7, za1, za3, za5, za7, 3)                                     \
  }

__global__ __launch_bounds__(64, 1)
void lstm_mfma_t(const int*   __restrict__ tokens,
                 const float* __restrict__ rec_kernel,  // [32][128] f32
                 const float* __restrict__ proj,        // [VOCAB][128] permuted+scaled
                 float*       __restrict__ out) {
  __shared__ int tokl[16][516];                         // 33 KiB, 2-way-free banks

  const int l   = threadIdx.x;
  const int g   = l >> 4;
  const int c16 = l & 15;
  const int g8  = g * 8;
  const int g4  = g * 4;

  // ---- stage tokens: 16 rows x 500 ints ----
  {
    const int4* src = reinterpret_cast<const int4*>(tokens + (size_t)blockIdx.x * 16 * T_N);
    for (int i = l; i < 16 * T_N / 4; i += 64) {
      int4 v4 = src[i];
      int gi = 4 * i;
      int r  = gi / T_N;                   // 500 % 4 == 0: no straddle
      int cc = gi - r * T_N;
      *reinterpret_cast<int4*>(&tokl[r][cc]) = v4;
    }
    for (int i = l; i < 16 * 16; i += 64) {
      int r = i >> 4; tokl[r][T_N + (i & 15)] = 0;
    }
  }

  // ---- static A-frags: A_n[row=c16][k=g8+j] = R[g8+j][map_col(16n+c16)]*sc ----
  bf16x8 Ah0, Ah1, Ah2, Ah3, Ah4, Ah5, Ah6, Ah7;
  bf16x8 Al0, Al1, Al2, Al3, Al4, Al5, Al6, Al7;
#define BUILD_A(N, AH, AL)                                                    \
  {                                                                           \
    const int Cn = map_col(16 * (N) + c16);                                   \
    const float sc = col_scale(N);                                            \
    _Pragma("unroll")                                                         \
    for (int j = 0; j < 8; ++j) {                                             \
      float x = rec_kernel[(g8 + j) * 128 + Cn] * sc;                         \
      unsigned s_ = bf16_split_pack(x);                                       \
      (AH)[j] = (short)s_; (AL)[j] = (short)(s_ >> 16);                       \
    }                                                                         \
  }
  BUILD_A(0, Ah0, Al0) BUILD_A(1, Ah1, Al1) BUILD_A(2, Ah2, Al2)
  BUILD_A(3, Ah3, Al3) BUILD_A(4, Ah4, Al4) BUILD_A(5, Ah5, Al5)
  BUILD_A(6, Ah6, Al6) BUILD_A(7, Ah7, Al7)
#undef BUILD_A

  asm volatile("s_waitcnt lgkmcnt(0)" ::: "memory");  // token staging visible (1 wave)

  // ---- state: packed h and f32 c for units g8+m, row c16 ----
  unsigned hp0 = 0, hp1 = 0, hp2 = 0, hp3 = 0, hp4 = 0, hp5 = 0, hp6 = 0, hp7 = 0;
  float    cc0 = 0.f, cc1 = 0.f, cc2 = 0.f, cc3 = 0.f,
           cc4 = 0.f, cc5 = 0.f, cc6 = 0.f, cc7 = 0.f;

  // ---- token pipeline (per-lane, row c16), 4 deep ----
  int tk0 = tokl[c16][0];
  int tk1 = tokl[c16][1];
  int tk2 = tokl[c16][2];
  int tk3 = tokl[c16][3];

  // ---- xp prologue: steps 0 and 1 ----
  float4 XA0, XA1, XA2, XA3, XA4, XA5, XA6, XA7;
  float4 XB0, XB1, XB2, XB3, XB4, XB5, XB6, XB7;
  {
    const float* pv = proj + ((size_t)(unsigned)tk0 << 7) + g4;
    XA0 = *reinterpret_cast<const float4*>(pv);
    XA1 = *reinterpret_cast<const float4*>(pv + 16);
    XA2 = *reinterpret_cast<const float4*>(pv + 32);
    XA3 = *reinterpret_cast<const float4*>(pv + 48);
    XA4 = *reinterpret_cast<const float4*>(pv + 64);
    XA5 = *reinterpret_cast<const float4*>(pv + 80);
    XA6 = *reinterpret_cast<const float4*>(pv + 96);
    XA7 = *reinterpret_cast<const float4*>(pv + 112);
    const float* pw = proj + ((size_t)(unsigned)tk1 << 7) + g4;
    XB0 = *reinterpret_cast<const float4*>(pw);
    XB1 = *reinterpret_cast<const float4*>(pw + 16);
    XB2 = *reinterpret_cast<const float4*>(pw + 32);
    XB3 = *reinterpret_cast<const float4*>(pw + 48);
    XB4 = *reinterpret_cast<const float4*>(pw + 64);
    XB5 = *reinterpret_cast<const float4*>(pw + 80);
    XB6 = *reinterpret_cast<const float4*>(pw + 96);
    XB7 = *reinterpret_cast<const float4*>(pw + 112);
  }

#pragma unroll 1
  for (int t = 0; t < T_N; t += 2) {
    int tn0 = tokl[c16][t + 4];
    int tn1 = tokl[c16][t + 5];

    MBODY(tk0, tk2, XA0, XA1, XA2, XA3, XA4, XA5, XA6, XA7);  // step t
    MBODY(tk1, tk3, XB0, XB1, XB2, XB3, XB4, XB5, XB6, XB7);  // step t+1

    tk0 = tk2; tk1 = tk3; tk2 = tn0; tk3 = tn1;
  }

  // ---- output: row c16, units g8..g8+7 ----
  float4 o0, o1;
  o0.x = unpack_h(hp0); o0.y = unpack_h(hp1); o0.z = unpack_h(hp2); o0.w = unpack_h(hp3);
  o1.x = unpack_h(hp4); o1.y = unpack_h(hp5); o1.z = unpack_h(hp6); o1.w = unpack_h(hp7);
  float* ob = out + ((size_t)blockIdx.x * 16 + c16) * HID_N + g8;
  *reinterpret_cast<float4*>(ob)     = o0;
  *reinterpret_cast<float4*>(ob + 4) = o1;
}

// ---------------------------------------------------------------------------
// Fallback (no workspace): proven round-1 kernel.
// ---------------------------------------------------------------------------
__device__ __forceinline__ float sigm_fb(float x) {
  return frcp(1.0f + exp2f(x * -1.4426950408889634f));
}
__device__ __forceinline__ float tanh_fb(float x) {
  float e = exp2f(x * 2.8853900817779268f);
  return fmaf(-2.0f, frcp(e + 1.0f), 1.0f);
}

__global__ __launch_bounds__(256, 2)
void lstm_scan_fallback(const int*   __restrict__ tokens,
                        const float* __restrict__ rec_kernel,
                        const float* __restrict__ emb,
                        const float* __restrict__ W,
                        const float* __restrict__ bias,
                        float*       __restrict__ out) {
  __shared__ int   tokl[8][T_N];
  __shared__ float hbuf[8][HID_N];

  const int tid  = threadIdx.x;
  const int wv   = tid >> 6;
  const int lane = tid & 63;
  const int half = lane >> 5;
  const int j    = lane & 31;
  const int wrow = wv * 2 + half;
  const int row  = blockIdx.x * 8 + wrow;

  {
    const int4* src = reinterpret_cast<const int4*>(tokens + (size_t)blockIdx.x * 8 * T_N);
    int4* dst = reinterpret_cast<int4*>(&tokl[0][0]);
    for (int i = tid; i < 8 * T_N / 4; i += 256) dst[i] = src[i];
  }

  float wr[HID_N][4];
#pragma unroll
  for (int k = 0; k < HID_N; ++k)
#pragma unroll
    for (int gg2 = 0; gg2 < 4; ++gg2) wr[k][gg2] = rec_kernel[k * 128 + gg2 * 32 + j];

  float wk[EMB_N][4];
  float bb[4];
#pragma unroll
  for (int e = 0; e < EMB_N; ++e)
#pragma unroll
    for (int gg2 = 0; gg2 < 4; ++gg2) wk[e][gg2] = W[e * 128 + gg2 * 32 + j];
#pragma unroll
  for (int gg2 = 0; gg2 < 4; ++gg2) bb[gg2] = bias[gg2 * 32 + j];
  __syncthreads();

  float c = 0.0f, h = 0.0f;
  float4 h4[8];
#pragma unroll
  for (int q = 0; q < 8; ++q) h4[q] = make_float4(0.f, 0.f, 0.f, 0.f);

  for (int t = 0; t < T_N; ++t) {
    const int tokc = tokl[wrow][t];
    const float4* ev = reinterpret_cast<const float4*>(emb + (size_t)tokc * EMB_N);
    float4 e0 = ev[0], e1 = ev[1], e2 = ev[2], e3 = ev[3];
    const float em[16] = {e0.x,e0.y,e0.z,e0.w, e1.x,e1.y,e1.z,e1.w,
                          e2.x,e2.y,e2.z,e2.w, e3.x,e3.y,e3.z,e3.w};
    float a0 = bb[0], a1 = bb[1], a2 = bb[2], a3 = bb[3];
#pragma unroll
    for (int e = 0; e < EMB_N; ++e) {
      float x = em[e];
      a0 = fmaf(x, wk[e][0], a0); a1 = fmaf(x, wk[e][1], a1);
      a2 = fmaf(x, wk[e][2], a2); a3 = fmaf(x, wk[e][3], a3);
    }
#pragma unroll
    for (int q = 0; q < 8; ++q) {
      float hx = h4[q].x, hy = h4[q].y, hz = h4[q].z, hw = h4[q].w;
      a0 = fmaf(hx, wr[4*q+0][0], a0); a1 = fmaf(hx, wr[4*q+0][1], a1);
      a2 = fmaf(hx, wr[4*q+0][2], a2); a3 = fmaf(hx, wr[4*q+0][3], a3);
      a0 = fmaf(hy, wr[4*q+1][0], a0); a1 = fmaf(hy, wr[4*q+1][1], a1);
      a2 = fmaf(hy, wr[4*q+1][2], a2); a3 = fmaf(hy, wr[4*q+1][3], a3);
      a0 = fmaf(hz, wr[4*q+2][0], a0); a1 = fmaf(hz, wr[4*q+2][1], a1);
      a2 = fmaf(hz, wr[4*q+2][2], a2); a3 = fmaf(hz, wr[4*q+2][3], a3);
      a0 = fmaf(hw, wr[4*q+3][0], a0); a1 = fmaf(hw, wr[4*q+3][1], a1);
      a2 = fmaf(hw, wr[4*q+3][2], a2); a3 = fmaf(hw, wr[4*q+3][3], a3);
    }
    float ig = sigm_fb(a0), fg = sigm_fb(a1), gg = tanh_fb(a2), og = sigm_fb(a3);
    float cn = fmaf(fg, c, ig * gg);
    float hn = og * tanh_fb(cn);
    if (tokc != 0) { h = hn; c = cn; }
    hbuf[wrow][j] = h;
    asm volatile("" ::: "memory");
#pragma unroll
    for (int q = 0; q < 8; ++q)
      h4[q] = reinterpret_cast<const float4*>(&hbuf[wrow][0])[q];
    asm volatile("" ::: "memory");
  }
  out[(size_t)row * HID_N + j] = h;
}

extern "C" void kernel_launch(void* const* d_in, const int* in_sizes, int n_in,
                              void* d_out, int out_size, void* d_ws, size_t ws_size,
                              hipStream_t stream) {
  const int*   tokens = (const int*)  d_in[0];
  const float* emb    = (const float*)d_in[1];
  const float* W      = (const float*)d_in[2];
  const float* rec    = (const float*)d_in[3];
  const float* bias   = (const float*)d_in[4];
  float* out = (float*)d_out;

  const size_t need = (size_t)VOCAB_N * 128 * sizeof(float);  // 25.6 MB
  if (ws_size >= need) {
    float* proj = (float*)d_ws;
    const long long total = (long long)VOCAB_N * 128;
    build_proj_t<<<(int)((total + 255) / 256), 256, 0, stream>>>(emb, W, bias, proj);
    lstm_mfma_t<<<B_N / 16, 64, 0, stream>>>(tokens, rec, proj, out);
  } else {
    lstm_scan_fallback<<<B_N / 8, 256, 0, stream>>>(tokens, rec, emb, W, bias, out);
  }
}

// Round 8
// 389.078 us; speedup vs baseline: 1.8242x; 1.8242x over previous
//
#include <hip/hip_runtime.h>
#include <cstdint>

#define VOCAB_N 50000
#define EMB_N   16
#define HID_N   32
#define B_N     4096
#define T_N     500

typedef __attribute__((ext_vector_type(2))) float f32x2;

__device__ __forceinline__ float frcp(float x) { return __builtin_amdgcn_rcpf(x); }
#define FMA2(A, B, C) __builtin_elementwise_fma((A), (B), (C))

// ---------------------------------------------------------------------------
// proj2[v][l] = { z_pre[l], z_pre[64+l] },  z_pre = bias + emb[v] . W
// ---------------------------------------------------------------------------
__global__ void build_proj2_kernel(const float* __restrict__ emb,
                                   const float* __restrict__ W,
                                   const float* __restrict__ bias,
                                   float2* __restrict__ proj2) {
  __shared__ float Wl[EMB_N * 128];
  __shared__ float bl[128];
  const int tid = threadIdx.x;
  for (int i = tid; i < EMB_N * 128 / 4; i += 256)
    reinterpret_cast<float4*>(Wl)[i] = reinterpret_cast<const float4*>(W)[i];
  if (tid < 32)
    reinterpret_cast<float4*>(bl)[tid] = reinterpret_cast<const float4*>(bias)[tid];
  __syncthreads();

  const int gid = blockIdx.x * 256 + tid;
  const int v = gid >> 6;
  const int l = gid & 63;
  if (v >= VOCAB_N) return;

  const float4* ev = reinterpret_cast<const float4*>(emb + (size_t)v * EMB_N);
  float4 e0 = ev[0], e1 = ev[1], e2 = ev[2], e3 = ev[3];
  const float em[16] = {e0.x,e0.y,e0.z,e0.w, e1.x,e1.y,e1.z,e1.w,
                        e2.x,e2.y,e2.z,e2.w, e3.x,e3.y,e3.z,e3.w};
  float a0 = bl[l], a1 = bl[64 + l];
#pragma unroll
  for (int e = 0; e < EMB_N; ++e) {
    a0 = fmaf(em[e], Wl[e * 128 + l],      a0);
    a1 = fmaf(em[e], Wl[e * 128 + 64 + l], a1);
  }
  proj2[(size_t)v * 64 + l] = make_float2(a0, a1);
}

// ---------------------------------------------------------------------------
// Scan: 1 wave per batch row (block = 64 thr, grid = 4096). Lane l owns
// z-cols {l, 64+l}. Recurrent matvec as 32 v_pk_fma_f32 over k-pairs:
// acc{even,odd} chains; h pairs come free as .xy/.zw of float4 LDS reads.
// Gates: R2's verified per-lane-constant trick + 2x shfl_xor(32).
// ---------------------------------------------------------------------------
#define KP(HX, HY, K2, AA, BB)                                                \
    (AA) = FMA2(((f32x2){(HX), (HY)}), wA[K2], (AA));                         \
    (BB) = FMA2(((f32x2){(HX), (HY)}), wB[K2], (BB));

#define STEP(STOK, PTOK, PC)                                                  \
  {                                                                           \
    float4 hq0 = *reinterpret_cast<const float4*>(hbuf + 0);                  \
    float4 hq1 = *reinterpret_cast<const float4*>(hbuf + 4);                  \
    float4 hq2 = *reinterpret_cast<const float4*>(hbuf + 8);                  \
    float4 hq3 = *reinterpret_cast<const float4*>(hbuf + 12);                 \
    float4 hq4 = *reinterpret_cast<const float4*>(hbuf + 16);                 \
    float4 hq5 = *reinterpret_cast<const float4*>(hbuf + 20);                 \
    float4 hq6 = *reinterpret_cast<const float4*>(hbuf + 24);                 \
    float4 hq7 = *reinterpret_cast<const float4*>(hbuf + 28);                 \
    const float xA = (PC).x, xB = (PC).y;                                     \
    (PC) = proj2[(size_t)(PTOK) * 64 + l];   /* prefetch t+2 */               \
    f32x2 a0 = {xA, 0.f}, a1 = {0.f, 0.f};                                    \
    f32x2 b0 = {xB, 0.f}, b1 = {0.f, 0.f};                                    \
    KP(hq0.x, hq0.y,  0, a0, b0)  KP(hq0.z, hq0.w,  1, a0, b0)                \
    KP(hq1.x, hq1.y,  2, a0, b0)  KP(hq1.z, hq1.w,  3, a0, b0)                \
    KP(hq2.x, hq2.y,  4, a0, b0)  KP(hq2.z, hq2.w,  5, a0, b0)                \
    KP(hq3.x, hq3.y,  6, a0, b0)  KP(hq3.z, hq3.w,  7, a0, b0)                \
    KP(hq4.x, hq4.y,  8, a1, b1)  KP(hq4.z, hq4.w,  9, a1, b1)                \
    KP(hq5.x, hq5.y, 10, a1, b1)  KP(hq5.z, hq5.w, 11, a1, b1)                \
    KP(hq6.x, hq6.y, 12, a1, b1)  KP(hq6.z, hq6.w, 13, a1, b1)                \
    KP(hq7.x, hq7.y, 14, a1, b1)  KP(hq7.z, hq7.w, 15, a1, b1)                \
    const float zA = (a0.x + a1.x) + (a0.y + a1.y);                           \
    const float zB = (b0.x + b1.x) + (b0.y + b1.y);                           \
    if ((STOK) != 0) {                       /* wave-uniform branch */        \
      float eA = exp2f(zA * -1.4426950408889634f);                            \
      float P  = frcp(1.0f + eA);                                             \
      float eB = exp2f(zB * sB);                                              \
      float rB = frcp(1.0f + eB);                                             \
      float Q  = fmaf(mB, rB, aB);                                            \
      float P2 = __shfl_xor(P, 32);                                           \
      float Q2 = __shfl_xor(Q, 32);                                           \
      float gi = lo ? P  : P2;                                                \
      float gf = lo ? P2 : P;                                                 \
      float gg = lo ? Q  : Q2;                                                \
      float go = lo ? Q2 : Q;                                                 \
      float cn = fmaf(gf, c, gi * gg);                                        \
      float eC = exp2f(cn * 2.8853900817779268f);                             \
      float tc = fmaf(-2.0f, frcp(1.0f + eC), 1.0f);                          \
      float hn = go * tc;                                                     \
      c = cn; h = hn;                                                         \
      hbuf[kidx] = hn;                                                        \
      asm volatile("" ::: "memory");                                          \
    }                                                                         \
  }

__global__ __launch_bounds__(64, 4)
void lstm_pk_kernel(const int*    __restrict__ tokens,
                    const float*  __restrict__ rec_kernel,  // [32][128]
                    const float2* __restrict__ proj2,       // [VOCAB][64]
                    float*        __restrict__ out) {
  __shared__ int   tokl[520];      // 500 + pad
  __shared__ float hbuf[32];

  const int l   = threadIdx.x;     // 0..63
  const int row = blockIdx.x;
  const int kidx = l & 31;

  // ---- stage tokens (1 row, 500 ints) ----
  {
    const int4* src = reinterpret_cast<const int4*>(tokens + (size_t)row * T_N);
    for (int i = l; i < T_N / 4; i += 64)
      *reinterpret_cast<int4*>(&tokl[4 * i]) = src[i];
    if (l < 20) tokl[T_N + l] = 0;
  }
  if (l < 32) hbuf[l] = 0.0f;
  asm volatile("" ::: "memory");   // staging before scan reads (DS in-order per wave)

  // ---- paired recurrent weights: wA[k2]={R[2k2][l],R[2k2+1][l]}, wB +64 ----
  f32x2 wA[16], wB[16];
#pragma unroll
  for (int k2 = 0; k2 < 16; ++k2) {
    wA[k2] = (f32x2){ rec_kernel[(2 * k2) * 128 + l],
                      rec_kernel[(2 * k2 + 1) * 128 + l] };
    wB[k2] = (f32x2){ rec_kernel[(2 * k2) * 128 + 64 + l],
                      rec_kernel[(2 * k2 + 1) * 128 + 64 + l] };
  }

  const bool lo = (l < 32);
  const float sB = lo ?  2.8853900817779268f : -1.4426950408889634f;
  const float mB = lo ? -2.0f : 1.0f;
  const float aB = lo ?  1.0f : 0.0f;

  float c = 0.0f, h = 0.0f;

  // ---- token pipeline, 4 deep (wave-uniform scalars) ----
  int t0 = __builtin_amdgcn_readfirstlane(tokl[0]);
  int t1 = __builtin_amdgcn_readfirstlane(tokl[1]);
  int t2 = __builtin_amdgcn_readfirstlane(tokl[2]);
  int t3 = __builtin_amdgcn_readfirstlane(tokl[3]);

  float2 p0 = proj2[(size_t)t0 * 64 + l];
  float2 p1 = proj2[(size_t)t1 * 64 + l];

#pragma unroll 1
  for (int t = 0; t < T_N; t += 2) {
    int2 tv = *reinterpret_cast<const int2*>(&tokl[t + 4]);

    STEP(t0, t2, p0);   // step t,   prefetch proj for t+2
    STEP(t1, t3, p1);   // step t+1, prefetch proj for t+3

    t0 = t2; t1 = t3;
    t2 = __builtin_amdgcn_readfirstlane(tv.x);
    t3 = __builtin_amdgcn_readfirstlane(tv.y);
  }

  if (l < 32) out[(size_t)row * HID_N + l] = h;
}

// ---------------------------------------------------------------------------
// Fallback (no workspace): proven round-1 kernel.
// ---------------------------------------------------------------------------
__device__ __forceinline__ float sigm_fb(float x) {
  return frcp(1.0f + exp2f(x * -1.4426950408889634f));
}
__device__ __forceinline__ float tanh_fb(float x) {
  float e = exp2f(x * 2.8853900817779268f);
  return fmaf(-2.0f, frcp(e + 1.0f), 1.0f);
}

__global__ __launch_bounds__(256, 2)
void lstm_scan_fallback(const int*   __restrict__ tokens,
                        const float* __restrict__ rec_kernel,
                        const float* __restrict__ emb,
                        const float* __restrict__ W,
                        const float* __restrict__ bias,
                        float*       __restrict__ out) {
  __shared__ int   tokl[8][T_N];
  __shared__ float hbuf[8][HID_N];

  const int tid  = threadIdx.x;
  const int wv   = tid >> 6;
  const int lane = tid & 63;
  const int half = lane >> 5;
  const int j    = lane & 31;
  const int wrow = wv * 2 + half;
  const int row  = blockIdx.x * 8 + wrow;

  {
    const int4* src = reinterpret_cast<const int4*>(tokens + (size_t)blockIdx.x * 8 * T_N);
    int4* dst = reinterpret_cast<int4*>(&tokl[0][0]);
    for (int i = tid; i < 8 * T_N / 4; i += 256) dst[i] = src[i];
  }

  float wr[HID_N][4];
#pragma unroll
  for (int k = 0; k < HID_N; ++k)
#pragma unroll
    for (int gg2 = 0; gg2 < 4; ++gg2) wr[k][gg2] = rec_kernel[k * 128 + gg2 * 32 + j];

  float wk[EMB_N][4];
  float bb[4];
#pragma unroll
  for (int e = 0; e < EMB_N; ++e)
#pragma unroll
    for (int gg2 = 0; gg2 < 4; ++gg2) wk[e][gg2] = W[e * 128 + gg2 * 32 + j];
#pragma unroll
  for (int gg2 = 0; gg2 < 4; ++gg2) bb[gg2] = bias[gg2 * 32 + j];
  __syncthreads();

  float c = 0.0f, h = 0.0f;
  float4 h4[8];
#pragma unroll
  for (int q = 0; q < 8; ++q) h4[q] = make_float4(0.f, 0.f, 0.f, 0.f);

  for (int t = 0; t < T_N; ++t) {
    const int tokc = tokl[wrow][t];
    const float4* ev = reinterpret_cast<const float4*>(emb + (size_t)tokc * EMB_N);
    float4 e0 = ev[0], e1 = ev[1], e2 = ev[2], e3 = ev[3];
    const float em[16] = {e0.x,e0.y,e0.z,e0.w, e1.x,e1.y,e1.z,e1.w,
                          e2.x,e2.y,e2.z,e2.w, e3.x,e3.y,e3.z,e3.w};
    float a0 = bb[0], a1 = bb[1], a2 = bb[2], a3 = bb[3];
#pragma unroll
    for (int e = 0; e < EMB_N; ++e) {
      float x = em[e];
      a0 = fmaf(x, wk[e][0], a0); a1 = fmaf(x, wk[e][1], a1);
      a2 = fmaf(x, wk[e][2], a2); a3 = fmaf(x, wk[e][3], a3);
    }
#pragma unroll
    for (int q = 0; q < 8; ++q) {
      float hx = h4[q].x, hy = h4[q].y, hz = h4[q].z, hw = h4[q].w;
      a0 = fmaf(hx, wr[4*q+0][0], a0); a1 = fmaf(hx, wr[4*q+0][1], a1);
      a2 = fmaf(hx, wr[4*q+0][2], a2); a3 = fmaf(hx, wr[4*q+0][3], a3);
      a0 = fmaf(hy, wr[4*q+1][0], a0); a1 = fmaf(hy, wr[4*q+1][1], a1);
      a2 = fmaf(hy, wr[4*q+1][2], a2); a3 = fmaf(hy, wr[4*q+1][3], a3);
      a0 = fmaf(hz, wr[4*q+2][0], a0); a1 = fmaf(hz, wr[4*q+2][1], a1);
      a2 = fmaf(hz, wr[4*q+2][2], a2); a3 = fmaf(hz, wr[4*q+2][3], a3);
      a0 = fmaf(hw, wr[4*q+3][0], a0); a1 = fmaf(hw, wr[4*q+3][1], a1);
      a2 = fmaf(hw, wr[4*q+3][2], a2); a3 = fmaf(hw, wr[4*q+3][3], a3);
    }
    float ig = sigm_fb(a0), fg = sigm_fb(a1), gg = tanh_fb(a2), og = sigm_fb(a3);
    float cn = fmaf(fg, c, ig * gg);
    float hn = og * tanh_fb(cn);
    if (tokc != 0) { h = hn; c = cn; }
    hbuf[wrow][j] = h;
    asm volatile("" ::: "memory");
#pragma unroll
    for (int q = 0; q < 8; ++q)
      h4[q] = reinterpret_cast<const float4*>(&hbuf[wrow][0])[q];
    asm volatile("" ::: "memory");
  }
  out[(size_t)row * HID_N + j] = h;
}

extern "C" void kernel_launch(void* const* d_in, const int* in_sizes, int n_in,
                              void* d_out, int out_size, void* d_ws, size_t ws_size,
                              hipStream_t stream) {
  const int*   tokens = (const int*)  d_in[0];
  const float* emb    = (const float*)d_in[1];
  const float* W      = (const float*)d_in[2];
  const float* rec    = (const float*)d_in[3];
  const float* bias   = (const float*)d_in[4];
  float* out = (float*)d_out;

  const size_t need = (size_t)VOCAB_N * 64 * sizeof(float2);  // 25.6 MB
  if (ws_size >= need) {
    float2* proj2 = (float2*)d_ws;
    build_proj2_kernel<<<(VOCAB_N * 64) / 256 + 1, 256, 0, stream>>>(emb, W, bias, proj2);
    lstm_pk_kernel<<<B_N, 64, 0, stream>>>(tokens, rec, proj2, out);
  } else {
    lstm_scan_fallback<<<B_N / 8, 256, 0, stream>>>(tokens, rec, emb, W, bias, out);
  }
}